// Round 10
// baseline (1989.278 us; speedup 1.0000x reference)
//
#include <hip/hip_runtime.h>
#include <hip/hip_bf16.h>

#define NN 20000
#define NE 320000
#define NL 12
#define BN_C 0.9999950000374997f

// Inputs/outputs are float32 on the wire (proven R5: dtype probe + pass at 1.5e-5).

// packed chi-count per residue (LETTERS='ARNDCQEGHILKMFPSTWYV'), 3 bits each;
// reference mask is prefix-structured: mask[res][i] = (i < nchi[res]).
#define CHI_PACK ( (0ull<<0)|(4ull<<3)|(2ull<<6)|(2ull<<9)|(1ull<<12)|(3ull<<15)|(3ull<<18)|(0ull<<21) \
                 | (2ull<<24)|(2ull<<27)|(2ull<<30)|(4ull<<33)|(3ull<<36)|(2ull<<39)|(0ull<<42)|(1ull<<45) \
                 | (1ull<<48)|(2ull<<51)|(2ull<<54)|(1ull<<57) )
__device__ __forceinline__ float chi_mask(int res, int i){
  int nchi = (int)((CHI_PACK >> (3*res)) & 7ull);
  return (i < nchi) ? 1.f : 0.f;
}

__device__ __forceinline__ float wsum(float v){
  #pragma unroll
  for (int off = 32; off > 0; off >>= 1) v += __shfl_xor(v, off);
  return v;
}
__device__ __forceinline__ float leaky(float x){
  return fmaxf(x, 0.f) + 0.2f*fminf(x, 0.f);
}

// ---------------- zero counters ----------------
__global__ __launch_bounds__(256) void k_init(int* p, int n){
  int i = blockIdx.x*256 + threadIdx.x;
  if (i < n) p[i] = 0;
}

// ---------------- ws-too-small marker ----------------
__global__ __launch_bounds__(256) void k_mark(float* out){
  int i = blockIdx.x*256 + threadIdx.x;
  if (i < NN) out[i] = 9.0f;
}

// ---------------- embeddings + degree histograms ----------------
__global__ __launch_bounds__(256) void k_pre(
    const float* __restrict__ Xsc, const float* __restrict__ Xbb,
    const float* __restrict__ Wsc, const float* __restrict__ bsc,
    const float* __restrict__ Wbb, const float* __restrict__ bbb,
    const int* __restrict__ scE, const int* __restrict__ bbE,
    float* __restrict__ sc, float* __restrict__ bbuf, int* cnt_sc, int* cnt_bb){
  int b = blockIdx.x, t = threadIdx.x;
  if (b < 5000){
    int tid = b*256 + t;
    int node = tid >> 6, d = tid & 63;
    float acc = bsc[d];
    #pragma unroll
    for (int k = 0; k < 21; k++) acc += Xsc[node*21+k] * Wsc[k*64+d];
    sc[tid] = fmaxf(acc, 0.f);
  } else if (b < 10000){
    int tid = (b-5000)*256 + t;
    int node = tid >> 6, d = tid & 63;
    float acc = bbb[d];
    #pragma unroll
    for (int k = 0; k < 12; k++) acc += Xbb[node*12+k] * Wbb[k*64+d];
    bbuf[tid] = fmaxf(acc, 0.f);
  } else if (b < 11250){
    int e = (b-10000)*256 + t;
    atomicAdd(&cnt_sc[scE[NE + e]], 1);
  } else {
    int e = (b-11250)*256 + t;
    atomicAdd(&cnt_bb[bbE[NE + e]], 1);
  }
}

// ---------------- scan (blocks 0,1) + rel-gate table (block 2) ----------------
__global__ __launch_bounds__(256) void k_scan(
    int* cnt_sc, int* cnt_bb, int* rp_sc, int* rp_bb,
    const float* __restrict__ resT, const float* __restrict__ rrW1,
    const float* __restrict__ rrb1, const float* __restrict__ rrW2,
    const float* __restrict__ rrb2, float* relTab){
  int t = threadIdx.x;
  if (blockIdx.x == 2){
    __shared__ float sRT[320], sW1[512], sB1[16], sW2[16];
    for (int i = t; i < 320; i += 256) sRT[i] = resT[i];
    for (int i = t; i < 512; i += 256) sW1[i] = rrW1[i];
    if (t < 16){ sB1[t] = rrb1[t]; sW2[t] = rrW2[t]; }
    __syncthreads();
    float b2v = rrb2[0];
    for (int p = t; p < 400; p += 256){
      int a = p / 20, c = p % 20;
      const float* ra = &sRT[a*16];
      const float* rc = &sRT[c*16];
      float z = b2v;
      #pragma unroll
      for (int j = 0; j < 16; j++){
        float h = sB1[j];
        #pragma unroll
        for (int i = 0; i < 16; i++) h += ra[i] * sW1[i*16+j];
        #pragma unroll
        for (int i = 0; i < 16; i++) h += rc[i] * sW1[(16+i)*16+j];
        z += fmaxf(h, 0.f) * sW2[j];
      }
      relTab[p] = 1.f / (1.f + __expf(-z));
    }
    return;
  }
  int* cnt = blockIdx.x ? cnt_bb : cnt_sc;
  int* rp  = blockIdx.x ? rp_bb  : rp_sc;
  __shared__ int s[256];
  const int CH = 79;
  int beg = t * CH;
  int sum = 0;
  for (int i = beg; i < beg + CH && i < NN; i++) sum += cnt[i];
  s[t] = sum; __syncthreads();
  for (int off = 1; off < 256; off <<= 1){
    int v = (t >= off) ? s[t-off] : 0;
    __syncthreads();
    s[t] += v;
    __syncthreads();
  }
  int run = (t == 0) ? 0 : s[t-1];
  for (int i = beg; i < beg + CH && i < NN; i++){
    int c = cnt[i];
    rp[i] = run;
    cnt[i] = run;      // cursor for scatter
    run += c;
  }
  if (t == 0) rp[NN] = NE;
}

// ---------------- scatter: perm_src + gated sorted edge attrs (into eaA) ----------------
__global__ __launch_bounds__(256) void k_scatter(
    const int* __restrict__ scE, const int* __restrict__ bbE, const int* __restrict__ rid,
    const float* __restrict__ relTab, const float* __restrict__ attrs,
    int* cur_sc, int* cur_bb, int* __restrict__ ps_sc, int* __restrict__ ps_bb,
    float* __restrict__ ea){
  int b = blockIdx.x, t = threadIdx.x;
  if (b < 1250){
    int e = b*256 + t;
    int s = scE[e], d = scE[NE + e];
    float rel = relTab[rid[s]*20 + rid[d]];
    float4 A = ((const float4*)attrs)[e*2];
    float4 B = ((const float4*)attrs)[e*2+1];
    A.x *= rel; A.y *= rel; A.z *= rel; A.w *= rel;
    B.x *= rel; B.y *= rel; B.z *= rel; B.w *= rel;
    int pos = atomicAdd(&cur_sc[d], 1);
    ps_sc[pos] = s;
    ((float4*)ea)[pos*2]   = A;
    ((float4*)ea)[pos*2+1] = B;
  } else {
    int e = (b-1250)*256 + t;
    int s = bbE[e], d = bbE[NE + e];
    int pos = atomicAdd(&cur_bb[d], 1);
    ps_bb[pos] = s;
  }
}

// ---------------- initial node_mm (layer 0) into xlA / xr / bs ----------------
// grid: [0,1250) sc, [1250,2500) bb; 256 threads
__global__ __launch_bounds__(256) void k_mm0(
    const float* __restrict__ sc, const float* __restrict__ bbv,
    const float* __restrict__ scWl, const float* __restrict__ scWr,
    const float* __restrict__ scRes, const float* __restrict__ scBias,
    const float* __restrict__ bbWl, const float* __restrict__ bbWr,
    const float* __restrict__ bbRes, const float* __restrict__ bbBias,
    float* __restrict__ xl, float* __restrict__ xr, float* __restrict__ bs){
  __shared__ float sx[1024];
  int b = blockIdx.x, t = threadIdx.x;
  bool is_sc = b < 1250;
  int tile = is_sc ? b : b - 1250;
  int goff = is_sc ? 0 : NN*64;
  const float* x  = is_sc ? sc : bbv;
  const float* Wl = is_sc ? scWl : bbWl;
  const float* Wr = is_sc ? scWr : bbWr;
  const float* Ws = is_sc ? scRes : bbRes;
  const float* bias = is_sc ? scBias : bbBias;
  for (int i = t; i < 1024; i += 256) sx[i] = x[tile*1024 + i];
  __syncthreads();
  int d = t & 63, r = t >> 6;
  float aL[4] = {0,0,0,0}, aR[4] = {0,0,0,0}, aB[4];
  float bv = bias[d];
  #pragma unroll
  for (int j = 0; j < 4; j++) aB[j] = bv;
  #pragma unroll 4
  for (int k = 0; k < 64; k++){
    float wl = Wl[k*64+d], wr = Wr[k*64+d], ws = Ws[k*64+d];
    #pragma unroll
    for (int j = 0; j < 4; j++){
      float xv = sx[(r + 4*j)*64 + k];
      aL[j] += xv*wl; aR[j] += xv*wr; aB[j] += xv*ws;
    }
  }
  #pragma unroll
  for (int j = 0; j < 4; j++){
    int n = tile*16 + r + 4*j;
    xl[goff + n*64+d] = aL[j]; xr[goff + n*64+d] = aR[j]; bs[goff + n*64+d] = aB[j];
  }
}

// ---------------- fused layer kernel ----------------
// blocks [0,1250): sc tile agg(l) -> LDS -> node_mm(l+1)
// blocks [1250,2500): bb same
// blocks [2500,2813): edge-update(l+1)  (ea ping-pong; reads ea_cur like agg)
// xl ping-pong (gathered cross-block); xr/bs tile-private -> single buffer.
// sc/bb written only at l==11 (consumed by k_heads).
__global__ __launch_bounds__(1024, 8) void k_layer(
    int l,
    float* __restrict__ sc, float* __restrict__ bbv,
    float* __restrict__ xlA, float* __restrict__ xlB,
    float* __restrict__ xr, float* __restrict__ bs,
    float* __restrict__ eaA, float* __restrict__ eaB,
    const int* __restrict__ rp_sc, const int* __restrict__ ps_sc,
    const int* __restrict__ rp_bb, const int* __restrict__ ps_bb,
    const float* __restrict__ We, const float* __restrict__ scAtt, const float* __restrict__ bbAtt,
    const float* __restrict__ scWl, const float* __restrict__ scWr,
    const float* __restrict__ scRes, const float* __restrict__ scBias,
    const float* __restrict__ bbWl, const float* __restrict__ bbWr,
    const float* __restrict__ bbRes, const float* __restrict__ bbBias,
    const float* __restrict__ euW1, const float* __restrict__ eub1,
    const float* __restrict__ eug, const float* __restrict__ eube,
    const float* __restrict__ euW2, const float* __restrict__ eub2){
  __shared__ float smem[1024];
  int b = blockIdx.x, t = threadIdx.x;
  const float* xl_c = (l & 1) ? xlB : xlA;
  float*       xl_n = (l & 1) ? xlA : xlB;
  const float* ea_c = (l & 1) ? eaB : eaA;
  float*       ea_n = (l & 1) ? eaA : eaB;
  if (b < 2500){
    bool is_sc = b < 1250;
    int tile = is_sc ? b : b - 1250;
    int goff = is_sc ? 0 : NN*64;
    int lane = t & 63, wid = t >> 6;
    int half = lane >> 5, l2 = lane & 31;
    int n = tile*16 + wid;
    const int* rp = is_sc ? rp_sc : rp_bb;
    const int* ps = is_sc ? ps_sc : ps_bb;
    const float2* xl2 = (const float2*)(xl_c + goff);
    float2 att2 = ((const float2*)((is_sc ? scAtt : bbAtt) + l*64))[l2];
    float2 w[8];
    if (is_sc){
      #pragma unroll
      for (int j = 0; j < 8; j++) w[j] = ((const float2*)(We + l*512 + j*64))[l2];
    }
    int beg = rp[n], end = rp[n+1];
    float2 xr2 = ((const float2*)(xr + goff))[n*32 + l2];
    float ox = 0.f, oy = 0.f, s = 0.f;
    if (beg < end){
      int last = end - 1;
      int ia = min(beg + half, last);
      int ib = min(beg + 2 + half, last);
      float2 vA = xl2[ps[ia]*32 + l2];
      float2 vB = xl2[ps[ib]*32 + l2];
      for (int eid = beg; eid < end; eid += 4){
        int nx = eid + 4;
        int ia_n = min(nx + half, last);
        int ib_n = min(nx + 2 + half, last);
        float2 vA_n = xl2[ps[ia_n]*32 + l2];
        float2 vB_n = xl2[ps[ib_n]*32 + l2];
        bool va = eid + half < end;
        bool vb = eid + 2 + half < end;
        float mAx = vA.x + xr2.x, mAy = vA.y + xr2.y;
        float mBx = vB.x + xr2.x, mBy = vB.y + xr2.y;
        if (is_sc){
          int cia = min(eid + half, last);
          int cib = min(eid + 2 + half, last);
          const float4* pa4 = (const float4*)(ea_c + (size_t)cia*8);
          float4 A = pa4[0], B = pa4[1];
          float av[8] = {A.x,A.y,A.z,A.w,B.x,B.y,B.z,B.w};
          #pragma unroll
          for (int j = 0; j < 8; j++){ mAx += av[j]*w[j].x; mAy += av[j]*w[j].y; }
          const float4* pb4 = (const float4*)(ea_c + (size_t)cib*8);
          A = pb4[0]; B = pb4[1];
          float bvv[8] = {A.x,A.y,A.z,A.w,B.x,B.y,B.z,B.w};
          #pragma unroll
          for (int j = 0; j < 8; j++){ mBx += bvv[j]*w[j].x; mBy += bvv[j]*w[j].y; }
        }
        float eA = leaky(mAx)*att2.x + leaky(mAy)*att2.y;
        float eB = leaky(mBx)*att2.x + leaky(mBy)*att2.y;
        #pragma unroll
        for (int off = 1; off <= 16; off <<= 1){
          eA += __shfl_xor(eA, off);
          eB += __shfl_xor(eB, off);
        }
        float pA = va ? __expf(eA) : 0.f;
        float pB = vb ? __expf(eB) : 0.f;
        ox += pA*vA.x + pB*vB.x;
        oy += pA*vA.y + pB*vB.y;
        s  += pA + pB;
        vA = vA_n; vB = vB_n;
      }
    }
    ox += __shfl_xor(ox, 32);
    oy += __shfl_xor(oy, 32);
    s  += __shfl_xor(s, 32);
    if (half == 0){
      float2 bsv = ((const float2*)(bs + goff))[n*32 + l2];
      float inv = 1.f/(s + 1e-16f);
      float2 r2;
      r2.x = ox*inv + bsv.x;
      r2.y = oy*inv + bsv.y;
      ((float2*)smem)[wid*32 + l2] = r2;
      if (l == NL-1) ((float2*)((is_sc ? sc : bbv)))[n*32 + l2] = r2;
    }
    __syncthreads();
    if (l < NL-1){
      int d = t & 63, rr = t >> 6;
      int wo = (l+1)*4096 + d;
      const float* Wl = is_sc ? scWl : bbWl;
      const float* Wr = is_sc ? scWr : bbWr;
      const float* Ws = is_sc ? scRes : bbRes;
      float aL = 0.f, aR = 0.f;
      float aB = (is_sc ? scBias : bbBias)[(l+1)*64 + d];
      #pragma unroll 4
      for (int k = 0; k < 64; k++){
        float xv = smem[rr*64 + k];
        aL += xv * Wl[wo + k*64];
        aR += xv * Wr[wo + k*64];
        aB += xv * Ws[wo + k*64];
      }
      int nn = tile*16 + rr;
      xl_n[goff + nn*64 + d] = aL;
      xr[goff + nn*64 + d] = aR;
      bs[goff + nn*64 + d] = aB;
    }
  } else {
    if (l >= NL-1) return;
    float* sW1 = smem;        float* sB1 = smem+128; float* sG  = smem+144;
    float* sBe = smem+160;    float* sW2 = smem+176; float* sB2 = smem+304;
    int l1 = l + 1;
    if (t < 128){ sW1[t] = euW1[l1*128+t]; sW2[t] = euW2[l1*128+t]; }
    if (t < 16){ sB1[t] = eub1[l1*16+t]; sG[t] = eug[l1*16+t]; sBe[t] = eube[l1*16+t]; }
    if (t < 8) sB2[t] = eub2[l1*8+t];
    __syncthreads();
    int e = (b - 2500)*1024 + t;
    if (e < NE){
      float4 A = ((const float4*)ea_c)[e*2];
      float4 B = ((const float4*)ea_c)[e*2+1];
      float a[8] = {A.x,A.y,A.z,A.w,B.x,B.y,B.z,B.w};
      float h[16];
      #pragma unroll
      for (int j = 0; j < 16; j++){
        float v = sB1[j];
        #pragma unroll
        for (int i = 0; i < 8; i++) v += a[i] * sW1[i*16+j];
        h[j] = fmaxf(v*BN_C*sG[j] + sBe[j], 0.f);
      }
      #pragma unroll
      for (int i = 0; i < 8; i++){
        float v = sB2[i] + a[i];
        #pragma unroll
        for (int j = 0; j < 16; j++) v += h[j] * sW2[j*8+i];
        a[i] = v;
      }
      ((float4*)ea_n)[e*2]   = make_float4(a[0],a[1],a[2],a[3]);
      ((float4*)ea_n)[e*2+1] = make_float4(a[4],a[5],a[6],a[7]);
    }
  }
}

// ---------------- heads: chi (sc) | fusion + v_com + backbone heads (bb) ----------------
__global__ __launch_bounds__(256) void k_heads(
    const float* __restrict__ sc, const float* __restrict__ bbv, const int* __restrict__ rid,
    const float* __restrict__ bnuW, const float* __restrict__ bnub,
    const float* __restrict__ bnug, const float* __restrict__ bnube,
    const float* __restrict__ afW, const float* __restrict__ afb,
    const float* __restrict__ afg, const float* __restrict__ afbe,
    const float* __restrict__ vcW1, const float* __restrict__ vcb1,
    const float* __restrict__ vcW2, const float* __restrict__ vcb2,
    const float* __restrict__ chiW, const float* __restrict__ chib,
    const float* __restrict__ adW1, const float* __restrict__ adW2,
    const float* __restrict__ bbhW1, const float* __restrict__ bbhb1,
    const float* __restrict__ phiW2, const float* __restrict__ psiW2,
    const float* __restrict__ xcaW2, const float* __restrict__ xcab2,
    const float* __restrict__ vcbW2, const float* __restrict__ vcbb2,
    float* __restrict__ out){
  __shared__ float sx[1024];
  __shared__ float sh[1024];
  __shared__ int srid[16];
  int b = blockIdx.x, t = threadIdx.x;
  int d = t & 63, r = t >> 6;
  if (b < 1250){
    int tile = b;
    for (int i = t; i < 1024; i += 256) sx[i] = sc[tile*1024 + i];
    if (t < 16) srid[t] = rid[tile*16 + t];
    __syncthreads();
    for (int i = 0; i < 4; i++){
      const float* W = chiW + i*4096;
      float acc[4] = {0,0,0,0};
      #pragma unroll 4
      for (int k = 0; k < 64; k++){
        float w = W[k*64+d];
        #pragma unroll
        for (int j = 0; j < 4; j++) acc[j] += sx[(r + 4*j)*64 + k] * w;
      }
      float bi = chib[i*64+d];
      #pragma unroll
      for (int j = 0; j < 4; j++){
        float mk = chi_mask(srid[r + 4*j], i);
        sh[(r + 4*j)*64 + d] = fmaxf(acc[j] + bi, 0.f) * mk;
      }
      __syncthreads();
      float a2[4] = {0,0,0,0};
      #pragma unroll 4
      for (int k = 0; k < 64; k++){
        float w = adW1[k*64+d];
        #pragma unroll
        for (int j = 0; j < 4; j++) a2[j] += sh[(r + 4*j)*64 + k] * w;
      }
      float w2 = adW2[d];
      #pragma unroll
      for (int j = 0; j < 4; j++){
        float p = wsum(fmaxf(a2[j], 0.f) * w2);
        if (d == 0) out[i*NN + tile*16 + r + 4*j] = p;
      }
      __syncthreads();
    }
  } else {
    int tile = b - 1250;
    for (int i = t; i < 1024; i += 256){ sx[i] = sc[tile*1024 + i]; sh[i] = bbv[tile*1024 + i]; }
    __syncthreads();
    float aU[4] = {0,0,0,0}, aV[4] = {0,0,0,0};
    #pragma unroll 4
    for (int k = 0; k < 64; k++){
      float wu = bnuW[k*64+d], wv = vcW1[k*64+d];
      #pragma unroll
      for (int j = 0; j < 4; j++){
        float xv = sx[(r + 4*j)*64 + k];
        aU[j] += xv*wu; aV[j] += xv*wv;
      }
    }
    float afwd = afW[d];
    float bnubd = bnub[d], bnugd = bnug[d], bnubed = bnube[d];
    float vcb1d = vcb1[d];
    float afbv = afb[0], afgv = afg[0], afbev = afbe[0];
    #pragma unroll
    for (int j = 0; j < 4; j++){
      int node = tile*16 + r + 4*j;
      float z = wsum(sx[(r + 4*j)*64 + d] * afwd);
      float attn = 1.f / (1.f + __expf(-((z + afbv)*BN_C*afgv + afbev)));
      float u = fmaxf((aU[j] + bnubd)*BN_C*bnugd + bnubed, 0.f);
      sh[(r + 4*j)*64 + d] += attn*u;
      float vh = fmaxf(aV[j] + vcb1d, 0.f);
      #pragma unroll
      for (int c = 0; c < 3; c++){
        float p = wsum(vh * vcW2[d*3+c]);
        if (d == 0) out[4*NN + node*3 + c] = p + vcb2[c];
      }
    }
    __syncthreads();
    for (int i = 0; i < 4; i++){
      const float* W = bbhW1 + i*4096;
      float acc[4] = {0,0,0,0};
      #pragma unroll 4
      for (int k = 0; k < 64; k++){
        float w = W[k*64+d];
        #pragma unroll
        for (int j = 0; j < 4; j++) acc[j] += sh[(r + 4*j)*64 + k] * w;
      }
      float bi = bbhb1[i*64+d];
      if (i < 2){
        float w2 = (i == 0) ? phiW2[d] : psiW2[d];
        #pragma unroll
        for (int j = 0; j < 4; j++){
          float p = wsum(fmaxf(acc[j] + bi, 0.f) * w2);
          if (d == 0) out[(7+i)*NN + tile*16 + r + 4*j] = p;
        }
      } else {
        const float* W2 = (i == 2) ? xcaW2 : vcbW2;
        const float* B2 = (i == 2) ? xcab2 : vcbb2;
        int off = (i == 2) ? 9*NN : 12*NN;
        #pragma unroll
        for (int j = 0; j < 4; j++){
          float h = fmaxf(acc[j] + bi, 0.f);
          #pragma unroll
          for (int c = 0; c < 3; c++){
            float p = wsum(h * W2[d*3+c]);
            if (d == 0) out[off + (tile*16 + r + 4*j)*3 + c] = p + B2[c];
          }
        }
      }
    }
  }
}

extern "C" __attribute__((visibility("default")))
void kernel_launch(void* const* d_in, const int* in_sizes, int n_in,
                   void* d_out, int out_size, void* d_ws, size_t ws_size,
                   hipStream_t stream) {
  (void)hipGetLastError();

  const float* Xsc   = (const float*)d_in[0];
  const float* Xbb   = (const float*)d_in[1];
  const float* attrs = (const float*)d_in[2];
  const int*  scE   = (const int*)d_in[3];
  const int*  bbE   = (const int*)d_in[4];
  const int*  rid   = (const int*)d_in[5];
  const float* scembW=(const float*)d_in[6];  const float* scembb=(const float*)d_in[7];
  const float* bbembW=(const float*)d_in[8];  const float* bbembb=(const float*)d_in[9];
  const float* resT  =(const float*)d_in[10];
  const float* rrW1  =(const float*)d_in[11]; const float* rrb1  =(const float*)d_in[12];
  const float* rrW2  =(const float*)d_in[13]; const float* rrb2  =(const float*)d_in[14];
  const float* scWl  =(const float*)d_in[15]; const float* scWr  =(const float*)d_in[16];
  const float* scWe  =(const float*)d_in[17]; const float* scAtt =(const float*)d_in[18];
  const float* scRes =(const float*)d_in[19]; const float* scBias=(const float*)d_in[20];
  const float* bbWl  =(const float*)d_in[21]; const float* bbWr  =(const float*)d_in[22];
  const float* bbAtt =(const float*)d_in[23]; const float* bbRes =(const float*)d_in[24];
  const float* bbBias=(const float*)d_in[25];
  const float* euW1  =(const float*)d_in[26]; const float* eub1  =(const float*)d_in[27];
  const float* eug   =(const float*)d_in[28]; const float* eube  =(const float*)d_in[29];
  const float* euW2  =(const float*)d_in[30]; const float* eub2  =(const float*)d_in[31];
  const float* bnuW  =(const float*)d_in[32]; const float* bnub  =(const float*)d_in[33];
  const float* bnug  =(const float*)d_in[34]; const float* bnube =(const float*)d_in[35];
  const float* afW   =(const float*)d_in[36]; const float* afb   =(const float*)d_in[37];
  const float* afg   =(const float*)d_in[38]; const float* afbe  =(const float*)d_in[39];
  const float* chiW  =(const float*)d_in[40]; const float* chib  =(const float*)d_in[41];
  const float* adW1  =(const float*)d_in[42]; const float* adW2  =(const float*)d_in[43];
  const float* vcW1  =(const float*)d_in[44]; const float* vcb1  =(const float*)d_in[45];
  const float* vcW2  =(const float*)d_in[46]; const float* vcb2  =(const float*)d_in[47];
  const float* bbhW1 =(const float*)d_in[48]; const float* bbhb1 =(const float*)d_in[49];
  const float* phiW2 =(const float*)d_in[50]; const float* psiW2 =(const float*)d_in[51];
  const float* xcaW2 =(const float*)d_in[52]; const float* xcab2 =(const float*)d_in[53];
  const float* vcbW2 =(const float*)d_in[54]; const float* vcbb2 =(const float*)d_in[55];
  float* out = (float*)d_out;

  // ws: relTab(1K) | sc,bb | xlA,xlB,xr,bs (each 2*NN*64) | eaA,eaB | ints  (~75 MB)
  size_t nfloats = (size_t)2*NN*64       // sc+bb
                 + (size_t)4*2*NN*64     // xlA,xlB,xr,bs
                 + (size_t)2*NE*8;       // eaA,eaB
  size_t nints = (size_t)2*(NN+1) + 2*NN + 2*NE;
  size_t need = 1024 + nfloats*4 + nints*4;
  if (ws_size < need){
    k_mark<<<(NN+255)/256, 256, 0, stream>>>(out);
    return;
  }
  float* relTab = (float*)d_ws;
  float* f = (float*)((char*)d_ws + 1024);
  float* sc    = f; f += NN*64;
  float* bbuf  = f; f += NN*64;
  float* xlA   = f; f += 2*NN*64;
  float* xlB   = f; f += 2*NN*64;
  float* xr    = f; f += 2*NN*64;
  float* bs    = f; f += 2*NN*64;
  float* eaA   = f; f += NE*8;
  float* eaB   = f; f += NE*8;
  int* ip = (int*)f;
  int* rp_sc  = ip; ip += NN+1;
  int* rp_bb  = ip; ip += NN+1;
  int* cnt_sc = ip; ip += NN;
  int* cnt_bb = ip; ip += NN;
  int* ps_sc  = ip; ip += NE;
  int* ps_bb  = ip; ip += NE;

  k_init<<<(2*NN + 255)/256, 256, 0, stream>>>(cnt_sc, 2*NN);
  k_pre<<<12500, 256, 0, stream>>>(Xsc, Xbb, scembW, scembb, bbembW, bbembb,
                                   scE, bbE, sc, bbuf, cnt_sc, cnt_bb);
  k_scan<<<3, 256, 0, stream>>>(cnt_sc, cnt_bb, rp_sc, rp_bb,
                                resT, rrW1, rrb1, rrW2, rrb2, relTab);
  k_scatter<<<2500, 256, 0, stream>>>(scE, bbE, rid, relTab, attrs,
                                      cnt_sc, cnt_bb, ps_sc, ps_bb, eaA);
  k_mm0<<<2500, 256, 0, stream>>>(sc, bbuf,
      scWl, scWr, scRes, scBias, bbWl, bbWr, bbRes, bbBias,
      xlA, xr, bs);
  for (int l = 0; l < NL; l++){
    k_layer<<<2813, 1024, 0, stream>>>(l, sc, bbuf,
        xlA, xlB, xr, bs, eaA, eaB,
        rp_sc, ps_sc, rp_bb, ps_bb,
        scWe, scAtt, bbAtt,
        scWl, scWr, scRes, scBias,
        bbWl, bbWr, bbRes, bbBias,
        euW1, eub1, eug, eube, euW2, eub2);
  }
  k_heads<<<2500, 256, 0, stream>>>(sc, bbuf, rid,
      bnuW, bnub, bnug, bnube, afW, afb, afg, afbe,
      vcW1, vcb1, vcW2, vcb2,
      chiW, chib, adW1, adW2, bbhW1, bbhb1,
      phiW2, psiW2, xcaW2, xcab2, vcbW2, vcbb2, out);
}

// Round 11
// 1708.349 us; speedup vs baseline: 1.1644x; 1.1644x over previous
//
#include <hip/hip_runtime.h>
#include <hip/hip_bf16.h>

#define NN 20000
#define NE 320000
#define NL 12
#define BN_C 0.9999950000374997f

// Inputs/outputs are float32 on the wire (proven R5: dtype probe + pass at 1.5e-5).
// R10 lesson: do NOT fuse agg with node_mm/edge-update — L2 thrash (347 MB HBM/layer).

// packed chi-count per residue (LETTERS='ARNDCQEGHILKMFPSTWYV'), 3 bits each;
// reference mask is prefix-structured: mask[res][i] = (i < nchi[res]).
#define CHI_PACK ( (0ull<<0)|(4ull<<3)|(2ull<<6)|(2ull<<9)|(1ull<<12)|(3ull<<15)|(3ull<<18)|(0ull<<21) \
                 | (2ull<<24)|(2ull<<27)|(2ull<<30)|(4ull<<33)|(3ull<<36)|(2ull<<39)|(0ull<<42)|(1ull<<45) \
                 | (1ull<<48)|(2ull<<51)|(2ull<<54)|(1ull<<57) )
__device__ __forceinline__ float chi_mask(int res, int i){
  int nchi = (int)((CHI_PACK >> (3*res)) & 7ull);
  return (i < nchi) ? 1.f : 0.f;
}

typedef float vf4 __attribute__((ext_vector_type(4)));
__device__ __forceinline__ vf4 ldnt4(const float* p){ return __builtin_nontemporal_load((const vf4*)p); }
__device__ __forceinline__ int  ldnti(const int* p){ return __builtin_nontemporal_load(p); }

__device__ __forceinline__ float wsum(float v){
  #pragma unroll
  for (int off = 32; off > 0; off >>= 1) v += __shfl_xor(v, off);
  return v;
}
__device__ __forceinline__ float leaky(float x){
  return fmaxf(x, 0.f) + 0.2f*fminf(x, 0.f);
}

// ---------------- zero counters ----------------
__global__ __launch_bounds__(256) void k_init(int* p, int n){
  int i = blockIdx.x*256 + threadIdx.x;
  if (i < n) p[i] = 0;
}

// ---------------- ws-too-small marker ----------------
__global__ __launch_bounds__(256) void k_mark(float* out){
  int i = blockIdx.x*256 + threadIdx.x;
  if (i < NN) out[i] = 9.0f;
}

// ---------------- embeddings + degree histograms ----------------
__global__ __launch_bounds__(256) void k_pre(
    const float* __restrict__ Xsc, const float* __restrict__ Xbb,
    const float* __restrict__ Wsc, const float* __restrict__ bsc,
    const float* __restrict__ Wbb, const float* __restrict__ bbb,
    const int* __restrict__ scE, const int* __restrict__ bbE,
    float* __restrict__ sc, float* __restrict__ bbuf, int* cnt_sc, int* cnt_bb){
  int b = blockIdx.x, t = threadIdx.x;
  if (b < 5000){
    int tid = b*256 + t;
    int node = tid >> 6, d = tid & 63;
    float acc = bsc[d];
    #pragma unroll
    for (int k = 0; k < 21; k++) acc += Xsc[node*21+k] * Wsc[k*64+d];
    sc[tid] = fmaxf(acc, 0.f);
  } else if (b < 10000){
    int tid = (b-5000)*256 + t;
    int node = tid >> 6, d = tid & 63;
    float acc = bbb[d];
    #pragma unroll
    for (int k = 0; k < 12; k++) acc += Xbb[node*12+k] * Wbb[k*64+d];
    bbuf[tid] = fmaxf(acc, 0.f);
  } else if (b < 11250){
    int e = (b-10000)*256 + t;
    atomicAdd(&cnt_sc[scE[NE + e]], 1);
  } else {
    int e = (b-11250)*256 + t;
    atomicAdd(&cnt_bb[bbE[NE + e]], 1);
  }
}

// ---------------- scan (blocks 0,1) + rel-gate table (block 2) ----------------
__global__ __launch_bounds__(256) void k_scan(
    int* cnt_sc, int* cnt_bb, int* rp_sc, int* rp_bb,
    const float* __restrict__ resT, const float* __restrict__ rrW1,
    const float* __restrict__ rrb1, const float* __restrict__ rrW2,
    const float* __restrict__ rrb2, float* relTab){
  int t = threadIdx.x;
  if (blockIdx.x == 2){
    __shared__ float sRT[320], sW1[512], sB1[16], sW2[16];
    for (int i = t; i < 320; i += 256) sRT[i] = resT[i];
    for (int i = t; i < 512; i += 256) sW1[i] = rrW1[i];
    if (t < 16){ sB1[t] = rrb1[t]; sW2[t] = rrW2[t]; }
    __syncthreads();
    float b2v = rrb2[0];
    for (int p = t; p < 400; p += 256){
      int a = p / 20, c = p % 20;
      const float* ra = &sRT[a*16];
      const float* rc = &sRT[c*16];
      float z = b2v;
      #pragma unroll
      for (int j = 0; j < 16; j++){
        float h = sB1[j];
        #pragma unroll
        for (int i = 0; i < 16; i++) h += ra[i] * sW1[i*16+j];
        #pragma unroll
        for (int i = 0; i < 16; i++) h += rc[i] * sW1[(16+i)*16+j];
        z += fmaxf(h, 0.f) * sW2[j];
      }
      relTab[p] = 1.f / (1.f + __expf(-z));
    }
    return;
  }
  int* cnt = blockIdx.x ? cnt_bb : cnt_sc;
  int* rp  = blockIdx.x ? rp_bb  : rp_sc;
  __shared__ int s[256];
  const int CH = 79;
  int beg = t * CH;
  int sum = 0;
  for (int i = beg; i < beg + CH && i < NN; i++) sum += cnt[i];
  s[t] = sum; __syncthreads();
  for (int off = 1; off < 256; off <<= 1){
    int v = (t >= off) ? s[t-off] : 0;
    __syncthreads();
    s[t] += v;
    __syncthreads();
  }
  int run = (t == 0) ? 0 : s[t-1];
  for (int i = beg; i < beg + CH && i < NN; i++){
    int c = cnt[i];
    rp[i] = run;
    cnt[i] = run;      // cursor for scatter
    run += c;
  }
  if (t == 0) rp[NN] = NE;
}

// ---------------- scatter: perm_src + gated sorted edge attrs ----------------
__global__ __launch_bounds__(256) void k_scatter(
    const int* __restrict__ scE, const int* __restrict__ bbE, const int* __restrict__ rid,
    const float* __restrict__ relTab, const float* __restrict__ attrs,
    int* cur_sc, int* cur_bb, int* __restrict__ ps_sc, int* __restrict__ ps_bb,
    float* __restrict__ ea){
  int b = blockIdx.x, t = threadIdx.x;
  if (b < 1250){
    int e = b*256 + t;
    int s = scE[e], d = scE[NE + e];
    float rel = relTab[rid[s]*20 + rid[d]];
    float4 A = ((const float4*)attrs)[e*2];
    float4 B = ((const float4*)attrs)[e*2+1];
    A.x *= rel; A.y *= rel; A.z *= rel; A.w *= rel;
    B.x *= rel; B.y *= rel; B.z *= rel; B.w *= rel;
    int pos = atomicAdd(&cur_sc[d], 1);
    ps_sc[pos] = s;
    ((float4*)ea)[pos*2]   = A;
    ((float4*)ea)[pos*2+1] = B;
  } else {
    int e = (b-1250)*256 + t;
    int s = bbE[e], d = bbE[NE + e];
    int pos = atomicAdd(&cur_bb[d], 1);
    ps_bb[pos] = s;
  }
}

// ---------------- per-layer: edge update + node matmuls ----------------
// grid roles: [0,1250) edge update, [1250,1875) sc node mm (32 nodes/blk),
//             [1875,2500) bb node mm (32 nodes/blk)
__global__ __launch_bounds__(256) void k_layer1(
    float* __restrict__ ea, int l,
    const float* __restrict__ euW1, const float* __restrict__ eub1,
    const float* __restrict__ eug, const float* __restrict__ eube,
    const float* __restrict__ euW2, const float* __restrict__ eub2,
    const float* __restrict__ sc, const float* __restrict__ bbv,
    const float* __restrict__ scWl, const float* __restrict__ scWr,
    const float* __restrict__ scRes, const float* __restrict__ scBias,
    const float* __restrict__ bbWl, const float* __restrict__ bbWr,
    const float* __restrict__ bbRes, const float* __restrict__ bbBias,
    float* __restrict__ xl_sc, float* __restrict__ xr_sc, float* __restrict__ bs_sc,
    float* __restrict__ xl_bb, float* __restrict__ xr_bb, float* __restrict__ bs_bb){
  __shared__ float smem[2048];
  int b = blockIdx.x, t = threadIdx.x;
  if (b < 1250){
    float* sW1 = smem;        float* sB1 = smem+128; float* sG  = smem+144;
    float* sBe = smem+160;    float* sW2 = smem+176; float* sB2 = smem+304;
    for (int i = t; i < 128; i += 256){ sW1[i] = euW1[l*128+i]; sW2[i] = euW2[l*128+i]; }
    if (t < 16){ sB1[t] = eub1[l*16+t]; sG[t] = eug[l*16+t]; sBe[t] = eube[l*16+t]; }
    if (t < 8) sB2[t] = eub2[l*8+t];
    __syncthreads();
    int e = b*256 + t;
    float4 A = ((const float4*)ea)[e*2];
    float4 B = ((const float4*)ea)[e*2+1];
    float a[8] = {A.x,A.y,A.z,A.w,B.x,B.y,B.z,B.w};
    float h[16];
    #pragma unroll
    for (int j = 0; j < 16; j++){
      float v = sB1[j];
      #pragma unroll
      for (int i = 0; i < 8; i++) v += a[i] * sW1[i*16+j];
      h[j] = fmaxf(v*BN_C*sG[j] + sBe[j], 0.f);
    }
    #pragma unroll
    for (int i = 0; i < 8; i++){
      float v = sB2[i] + a[i];
      #pragma unroll
      for (int j = 0; j < 16; j++) v += h[j] * sW2[j*8+i];
      a[i] = v;
    }
    ((float4*)ea)[e*2]   = make_float4(a[0],a[1],a[2],a[3]);
    ((float4*)ea)[e*2+1] = make_float4(a[4],a[5],a[6],a[7]);
  } else {
    bool is_sc = b < 1875;
    int tile = is_sc ? (b-1250) : (b-1875);
    const float* x  = is_sc ? sc : bbv;
    const float* Wl = is_sc ? scWl : bbWl;
    const float* Wr = is_sc ? scWr : bbWr;
    const float* Ws = is_sc ? scRes : bbRes;
    const float* bias = is_sc ? scBias : bbBias;
    float* xl = is_sc ? xl_sc : xl_bb;
    float* xr = is_sc ? xr_sc : xr_bb;
    float* bs = is_sc ? bs_sc : bs_bb;
    for (int i = t; i < 2048; i += 256) smem[i] = x[tile*2048 + i];
    __syncthreads();
    int d = t & 63, r = t >> 6;
    int wo = l*4096 + d;
    float aL[8] = {0,0,0,0,0,0,0,0}, aR[8] = {0,0,0,0,0,0,0,0}, aB[8];
    float bv = bias[l*64 + d];
    #pragma unroll
    for (int j = 0; j < 8; j++) aB[j] = bv;
    #pragma unroll 2
    for (int k = 0; k < 64; k++){
      float wl = Wl[wo + k*64], wr = Wr[wo + k*64], ws = Ws[wo + k*64];
      #pragma unroll
      for (int j = 0; j < 8; j++){
        float xv = smem[(r + 4*j)*64 + k];
        aL[j] += xv*wl; aR[j] += xv*wr; aB[j] += xv*ws;
      }
    }
    int n0 = tile*32 + r;
    #pragma unroll
    for (int j = 0; j < 8; j++){
      int n = n0 + 4*j;
      xl[n*64+d] = aL[j]; xr[n*64+d] = aR[j]; bs[n*64+d] = aB[j];
    }
  }
}

// ---------------- GAT aggregation: half-wave per edge + gather prefetch ----------------
// XCD-aware swizzle: with round-robin block->XCD dispatch, (blockIdx&7)<4 -> sc,
// >=4 -> bb, so each XCD's L2 caches only ONE graph's 5MB gather array.
// ea/ps streams are non-temporal (zero reuse within this kernel) to keep
// gather lines resident. grid 10000 x 256 (4 waves = 4 nodes per block).
__global__ __launch_bounds__(256) void k_agg(
    float* __restrict__ sc, float* __restrict__ bbv, int l,
    const float* __restrict__ xl_sc, const float* __restrict__ xr_sc, const float* __restrict__ bs_sc,
    const float* __restrict__ xl_bb, const float* __restrict__ xr_bb, const float* __restrict__ bs_bb,
    const int* __restrict__ rp_sc, const int* __restrict__ ps_sc,
    const int* __restrict__ rp_bb, const int* __restrict__ ps_bb,
    const float* __restrict__ ea, const float* __restrict__ We,
    const float* __restrict__ scAtt, const float* __restrict__ bbAtt){
  int x = blockIdx.x;
  int lane = threadIdx.x & 63, wid = threadIdx.x >> 6;
  int half = lane >> 5, l2 = lane & 31;
  int xcd = x & 7;
  bool is_sc = xcd < 4;
  int n = ((x >> 3)*4 + (xcd & 3))*4 + wid;
  const float* xl = is_sc ? xl_sc : xl_bb;
  const float* xr = is_sc ? xr_sc : xr_bb;
  const float* bs = is_sc ? bs_sc : bs_bb;
  const int* rp = is_sc ? rp_sc : rp_bb;
  const int* ps = is_sc ? ps_sc : ps_bb;
  const float2* xl2 = (const float2*)xl;
  float2 att2 = ((const float2*)((is_sc ? scAtt : bbAtt) + l*64))[l2];
  float2 w[8];
  if (is_sc){
    #pragma unroll
    for (int j = 0; j < 8; j++) w[j] = ((const float2*)(We + l*512 + j*64))[l2];
  }
  int beg = rp[n], end = rp[n+1];
  float2 xr2 = ((const float2*)xr)[n*32 + l2];
  float ox = 0.f, oy = 0.f, s = 0.f;
  if (beg < end){
    int last = end - 1;
    int ia = min(beg + half, last);
    int ib = min(beg + 2 + half, last);
    float2 vA = xl2[ldnti(ps + ia)*32 + l2];
    float2 vB = xl2[ldnti(ps + ib)*32 + l2];
    for (int eid = beg; eid < end; eid += 4){
      int nx = eid + 4;
      int ia_n = min(nx + half, last);
      int ib_n = min(nx + 2 + half, last);
      float2 vA_n = xl2[ldnti(ps + ia_n)*32 + l2];
      float2 vB_n = xl2[ldnti(ps + ib_n)*32 + l2];
      bool va = eid + half < end;
      bool vb = eid + 2 + half < end;
      float mAx = vA.x + xr2.x, mAy = vA.y + xr2.y;
      float mBx = vB.x + xr2.x, mBy = vB.y + xr2.y;
      if (is_sc){
        int cia = min(eid + half, last);
        int cib = min(eid + 2 + half, last);
        vf4 A = ldnt4(ea + (size_t)cia*8);
        vf4 B = ldnt4(ea + (size_t)cia*8 + 4);
        float av[8] = {A.x,A.y,A.z,A.w,B.x,B.y,B.z,B.w};
        #pragma unroll
        for (int j = 0; j < 8; j++){ mAx += av[j]*w[j].x; mAy += av[j]*w[j].y; }
        A = ldnt4(ea + (size_t)cib*8);
        B = ldnt4(ea + (size_t)cib*8 + 4);
        float bvv[8] = {A.x,A.y,A.z,A.w,B.x,B.y,B.z,B.w};
        #pragma unroll
        for (int j = 0; j < 8; j++){ mBx += bvv[j]*w[j].x; mBy += bvv[j]*w[j].y; }
      }
      float eA = leaky(mAx)*att2.x + leaky(mAy)*att2.y;
      float eB = leaky(mBx)*att2.x + leaky(mBy)*att2.y;
      #pragma unroll
      for (int off = 1; off <= 16; off <<= 1){
        eA += __shfl_xor(eA, off);
        eB += __shfl_xor(eB, off);
      }
      float pA = va ? __expf(eA) : 0.f;
      float pB = vb ? __expf(eB) : 0.f;
      ox += pA*vA.x + pB*vB.x;
      oy += pA*vA.y + pB*vB.y;
      s  += pA + pB;
      vA = vA_n; vB = vB_n;
    }
  }
  ox += __shfl_xor(ox, 32);
  oy += __shfl_xor(oy, 32);
  s  += __shfl_xor(s, 32);
  if (half == 0){
    float2 bsv = ((const float2*)bs)[n*32 + l2];
    float inv = 1.f/(s + 1e-16f);
    float2 r;
    r.x = ox*inv + bsv.x;
    r.y = oy*inv + bsv.y;
    ((float2*)(is_sc ? sc : bbv))[n*32 + l2] = r;
  }
}

// ---------------- heads: chi (sc) | fusion + v_com + backbone heads (bb) ----------------
__global__ __launch_bounds__(256) void k_heads(
    const float* __restrict__ sc, const float* __restrict__ bbv, const int* __restrict__ rid,
    const float* __restrict__ bnuW, const float* __restrict__ bnub,
    const float* __restrict__ bnug, const float* __restrict__ bnube,
    const float* __restrict__ afW, const float* __restrict__ afb,
    const float* __restrict__ afg, const float* __restrict__ afbe,
    const float* __restrict__ vcW1, const float* __restrict__ vcb1,
    const float* __restrict__ vcW2, const float* __restrict__ vcb2,
    const float* __restrict__ chiW, const float* __restrict__ chib,
    const float* __restrict__ adW1, const float* __restrict__ adW2,
    const float* __restrict__ bbhW1, const float* __restrict__ bbhb1,
    const float* __restrict__ phiW2, const float* __restrict__ psiW2,
    const float* __restrict__ xcaW2, const float* __restrict__ xcab2,
    const float* __restrict__ vcbW2, const float* __restrict__ vcbb2,
    float* __restrict__ out){
  __shared__ float sx[1024];
  __shared__ float sh[1024];
  __shared__ int srid[16];
  int b = blockIdx.x, t = threadIdx.x;
  int d = t & 63, r = t >> 6;
  if (b < 1250){
    int tile = b;
    for (int i = t; i < 1024; i += 256) sx[i] = sc[tile*1024 + i];
    if (t < 16) srid[t] = rid[tile*16 + t];
    __syncthreads();
    for (int i = 0; i < 4; i++){
      const float* W = chiW + i*4096;
      float acc[4] = {0,0,0,0};
      #pragma unroll 4
      for (int k = 0; k < 64; k++){
        float w = W[k*64+d];
        #pragma unroll
        for (int j = 0; j < 4; j++) acc[j] += sx[(r + 4*j)*64 + k] * w;
      }
      float bi = chib[i*64+d];
      #pragma unroll
      for (int j = 0; j < 4; j++){
        float mk = chi_mask(srid[r + 4*j], i);
        sh[(r + 4*j)*64 + d] = fmaxf(acc[j] + bi, 0.f) * mk;
      }
      __syncthreads();
      float a2[4] = {0,0,0,0};
      #pragma unroll 4
      for (int k = 0; k < 64; k++){
        float w = adW1[k*64+d];
        #pragma unroll
        for (int j = 0; j < 4; j++) a2[j] += sh[(r + 4*j)*64 + k] * w;
      }
      float w2 = adW2[d];
      #pragma unroll
      for (int j = 0; j < 4; j++){
        float p = wsum(fmaxf(a2[j], 0.f) * w2);
        if (d == 0) out[i*NN + tile*16 + r + 4*j] = p;
      }
      __syncthreads();
    }
  } else {
    int tile = b - 1250;
    for (int i = t; i < 1024; i += 256){ sx[i] = sc[tile*1024 + i]; sh[i] = bbv[tile*1024 + i]; }
    __syncthreads();
    float aU[4] = {0,0,0,0}, aV[4] = {0,0,0,0};
    #pragma unroll 4
    for (int k = 0; k < 64; k++){
      float wu = bnuW[k*64+d], wv = vcW1[k*64+d];
      #pragma unroll
      for (int j = 0; j < 4; j++){
        float xv = sx[(r + 4*j)*64 + k];
        aU[j] += xv*wu; aV[j] += xv*wv;
      }
    }
    float afwd = afW[d];
    float bnubd = bnub[d], bnugd = bnug[d], bnubed = bnube[d];
    float vcb1d = vcb1[d];
    float afbv = afb[0], afgv = afg[0], afbev = afbe[0];
    #pragma unroll
    for (int j = 0; j < 4; j++){
      int node = tile*16 + r + 4*j;
      float z = wsum(sx[(r + 4*j)*64 + d] * afwd);
      float attn = 1.f / (1.f + __expf(-((z + afbv)*BN_C*afgv + afbev)));
      float u = fmaxf((aU[j] + bnubd)*BN_C*bnugd + bnubed, 0.f);
      sh[(r + 4*j)*64 + d] += attn*u;
      float vh = fmaxf(aV[j] + vcb1d, 0.f);
      #pragma unroll
      for (int c = 0; c < 3; c++){
        float p = wsum(vh * vcW2[d*3+c]);
        if (d == 0) out[4*NN + node*3 + c] = p + vcb2[c];
      }
    }
    __syncthreads();
    for (int i = 0; i < 4; i++){
      const float* W = bbhW1 + i*4096;
      float acc[4] = {0,0,0,0};
      #pragma unroll 4
      for (int k = 0; k < 64; k++){
        float w = W[k*64+d];
        #pragma unroll
        for (int j = 0; j < 4; j++) acc[j] += sh[(r + 4*j)*64 + k] * w;
      }
      float bi = bbhb1[i*64+d];
      if (i < 2){
        float w2 = (i == 0) ? phiW2[d] : psiW2[d];
        #pragma unroll
        for (int j = 0; j < 4; j++){
          float p = wsum(fmaxf(acc[j] + bi, 0.f) * w2);
          if (d == 0) out[(7+i)*NN + tile*16 + r + 4*j] = p;
        }
      } else {
        const float* W2 = (i == 2) ? xcaW2 : vcbW2;
        const float* B2 = (i == 2) ? xcab2 : vcbb2;
        int off = (i == 2) ? 9*NN : 12*NN;
        #pragma unroll
        for (int j = 0; j < 4; j++){
          float h = fmaxf(acc[j] + bi, 0.f);
          #pragma unroll
          for (int c = 0; c < 3; c++){
            float p = wsum(h * W2[d*3+c]);
            if (d == 0) out[off + (tile*16 + r + 4*j)*3 + c] = p + B2[c];
          }
        }
      }
    }
  }
}

extern "C" __attribute__((visibility("default")))
void kernel_launch(void* const* d_in, const int* in_sizes, int n_in,
                   void* d_out, int out_size, void* d_ws, size_t ws_size,
                   hipStream_t stream) {
  (void)hipGetLastError();

  const float* Xsc   = (const float*)d_in[0];
  const float* Xbb   = (const float*)d_in[1];
  const float* attrs = (const float*)d_in[2];
  const int*  scE   = (const int*)d_in[3];
  const int*  bbE   = (const int*)d_in[4];
  const int*  rid   = (const int*)d_in[5];
  const float* scembW=(const float*)d_in[6];  const float* scembb=(const float*)d_in[7];
  const float* bbembW=(const float*)d_in[8];  const float* bbembb=(const float*)d_in[9];
  const float* resT  =(const float*)d_in[10];
  const float* rrW1  =(const float*)d_in[11]; const float* rrb1  =(const float*)d_in[12];
  const float* rrW2  =(const float*)d_in[13]; const float* rrb2  =(const float*)d_in[14];
  const float* scWl  =(const float*)d_in[15]; const float* scWr  =(const float*)d_in[16];
  const float* scWe  =(const float*)d_in[17]; const float* scAtt =(const float*)d_in[18];
  const float* scRes =(const float*)d_in[19]; const float* scBias=(const float*)d_in[20];
  const float* bbWl  =(const float*)d_in[21]; const float* bbWr  =(const float*)d_in[22];
  const float* bbAtt =(const float*)d_in[23]; const float* bbRes =(const float*)d_in[24];
  const float* bbBias=(const float*)d_in[25];
  const float* euW1  =(const float*)d_in[26]; const float* eub1  =(const float*)d_in[27];
  const float* eug   =(const float*)d_in[28]; const float* eube  =(const float*)d_in[29];
  const float* euW2  =(const float*)d_in[30]; const float* eub2  =(const float*)d_in[31];
  const float* bnuW  =(const float*)d_in[32]; const float* bnub  =(const float*)d_in[33];
  const float* bnug  =(const float*)d_in[34]; const float* bnube =(const float*)d_in[35];
  const float* afW   =(const float*)d_in[36]; const float* afb   =(const float*)d_in[37];
  const float* afg   =(const float*)d_in[38]; const float* afbe  =(const float*)d_in[39];
  const float* chiW  =(const float*)d_in[40]; const float* chib  =(const float*)d_in[41];
  const float* adW1  =(const float*)d_in[42]; const float* adW2  =(const float*)d_in[43];
  const float* vcW1  =(const float*)d_in[44]; const float* vcb1  =(const float*)d_in[45];
  const float* vcW2  =(const float*)d_in[46]; const float* vcb2  =(const float*)d_in[47];
  const float* bbhW1 =(const float*)d_in[48]; const float* bbhb1 =(const float*)d_in[49];
  const float* phiW2 =(const float*)d_in[50]; const float* psiW2 =(const float*)d_in[51];
  const float* xcaW2 =(const float*)d_in[52]; const float* xcab2 =(const float*)d_in[53];
  const float* vcbW2 =(const float*)d_in[54]; const float* vcbb2 =(const float*)d_in[55];
  float* out = (float*)d_out;

  size_t need = 1024 + (size_t)(8*NN*64 + NE*8)*4 + (size_t)(2*(NN+1) + 2*NN + 2*NE)*4;
  if (ws_size < need){
    k_mark<<<(NN+255)/256, 256, 0, stream>>>(out);
    return;
  }
  float* relTab = (float*)d_ws;
  float* f = (float*)((char*)d_ws + 1024);
  float* sc    = f; f += NN*64;
  float* bbuf  = f; f += NN*64;
  float* xl_sc = f; f += NN*64;
  float* xr_sc = f; f += NN*64;
  float* bs_sc = f; f += NN*64;
  float* xl_bb = f; f += NN*64;
  float* xr_bb = f; f += NN*64;
  float* bs_bb = f; f += NN*64;
  float* ea    = f; f += NE*8;
  int* ip = (int*)f;
  int* rp_sc  = ip; ip += NN+1;
  int* rp_bb  = ip; ip += NN+1;
  int* cnt_sc = ip; ip += NN;
  int* cnt_bb = ip; ip += NN;
  int* ps_sc  = ip; ip += NE;
  int* ps_bb  = ip; ip += NE;

  k_init<<<(2*NN + 255)/256, 256, 0, stream>>>(cnt_sc, 2*NN);
  k_pre<<<12500, 256, 0, stream>>>(Xsc, Xbb, scembW, scembb, bbembW, bbembb,
                                   scE, bbE, sc, bbuf, cnt_sc, cnt_bb);
  k_scan<<<3, 256, 0, stream>>>(cnt_sc, cnt_bb, rp_sc, rp_bb,
                                resT, rrW1, rrb1, rrW2, rrb2, relTab);
  k_scatter<<<2500, 256, 0, stream>>>(scE, bbE, rid, relTab, attrs,
                                      cnt_sc, cnt_bb, ps_sc, ps_bb, ea);
  for (int l = 0; l < NL; l++){
    k_layer1<<<2500, 256, 0, stream>>>(ea, l,
        euW1, eub1, eug, eube, euW2, eub2,
        sc, bbuf,
        scWl, scWr, scRes, scBias,
        bbWl, bbWr, bbRes, bbBias,
        xl_sc, xr_sc, bs_sc, xl_bb, xr_bb, bs_bb);
    k_agg<<<10000, 256, 0, stream>>>(sc, bbuf, l,
        xl_sc, xr_sc, bs_sc, xl_bb, xr_bb, bs_bb,
        rp_sc, ps_sc, rp_bb, ps_bb,
        ea, scWe, scAtt, bbAtt);
  }
  k_heads<<<2500, 256, 0, stream>>>(sc, bbuf, rid,
      bnuW, bnub, bnug, bnube, afW, afb, afg, afbe,
      vcW1, vcb1, vcW2, vcb2,
      chiW, chib, adW1, adW2, bbhW1, bbhb1,
      phiW2, psiW2, xcaW2, xcab2, vcbW2, vcbb2, out);
}

// Round 12
// 1331.346 us; speedup vs baseline: 1.4942x; 1.2832x over previous
//
#include <hip/hip_runtime.h>
#include <hip/hip_bf16.h>

#define NN 20000
#define NE 320000
#define NL 12
#define BN_C 0.9999950000374997f

// Inputs/outputs are float32 on the wire (proven R5).
// R10 lesson: do NOT fuse agg with node_mm/edge-update — L2 thrash (347 MB HBM/layer).
// R11 lesson: do NOT pin sc-graph to an XCD subset — sc edges cost ~2.3x bb, idles half the chip.

// packed chi-count per residue (LETTERS='ARNDCQEGHILKMFPSTWYV'), 3 bits each;
// reference mask is prefix-structured: mask[res][i] = (i < nchi[res]).
#define CHI_PACK ( (0ull<<0)|(4ull<<3)|(2ull<<6)|(2ull<<9)|(1ull<<12)|(3ull<<15)|(3ull<<18)|(0ull<<21) \
                 | (2ull<<24)|(2ull<<27)|(2ull<<30)|(4ull<<33)|(3ull<<36)|(2ull<<39)|(0ull<<42)|(1ull<<45) \
                 | (1ull<<48)|(2ull<<51)|(2ull<<54)|(1ull<<57) )
__device__ __forceinline__ float chi_mask(int res, int i){
  int nchi = (int)((CHI_PACK >> (3*res)) & 7ull);
  return (i < nchi) ? 1.f : 0.f;
}

__device__ __forceinline__ float wsum(float v){
  #pragma unroll
  for (int off = 32; off > 0; off >>= 1) v += __shfl_xor(v, off);
  return v;
}
__device__ __forceinline__ float leaky(float x){
  return fmaxf(x, 0.f) + 0.2f*fminf(x, 0.f);
}
__device__ __forceinline__ float f4c(const float4& v, int kk){
  return kk==0 ? v.x : kk==1 ? v.y : kk==2 ? v.z : v.w;
}

// ---------------- zero counters ----------------
__global__ __launch_bounds__(256) void k_init(int* p, int n){
  int i = blockIdx.x*256 + threadIdx.x;
  if (i < n) p[i] = 0;
}

// ---------------- ws-too-small marker ----------------
__global__ __launch_bounds__(256) void k_mark(float* out){
  int i = blockIdx.x*256 + threadIdx.x;
  if (i < NN) out[i] = 9.0f;
}

// ---------------- embeddings + degree histograms ----------------
__global__ __launch_bounds__(256) void k_pre(
    const float* __restrict__ Xsc, const float* __restrict__ Xbb,
    const float* __restrict__ Wsc, const float* __restrict__ bsc,
    const float* __restrict__ Wbb, const float* __restrict__ bbb,
    const int* __restrict__ scE, const int* __restrict__ bbE,
    float* __restrict__ sc, float* __restrict__ bbuf, int* cnt_sc, int* cnt_bb){
  int b = blockIdx.x, t = threadIdx.x;
  if (b < 5000){
    int tid = b*256 + t;
    int node = tid >> 6, d = tid & 63;
    float acc = bsc[d];
    #pragma unroll
    for (int k = 0; k < 21; k++) acc += Xsc[node*21+k] * Wsc[k*64+d];
    sc[tid] = fmaxf(acc, 0.f);
  } else if (b < 10000){
    int tid = (b-5000)*256 + t;
    int node = tid >> 6, d = tid & 63;
    float acc = bbb[d];
    #pragma unroll
    for (int k = 0; k < 12; k++) acc += Xbb[node*12+k] * Wbb[k*64+d];
    bbuf[tid] = fmaxf(acc, 0.f);
  } else if (b < 11250){
    int e = (b-10000)*256 + t;
    atomicAdd(&cnt_sc[scE[NE + e]], 1);
  } else {
    int e = (b-11250)*256 + t;
    atomicAdd(&cnt_bb[bbE[NE + e]], 1);
  }
}

// ---------------- scan (blocks 0,1) + rel-gate table (block 2) ----------------
__global__ __launch_bounds__(256) void k_scan(
    int* cnt_sc, int* cnt_bb, int* rp_sc, int* rp_bb,
    const float* __restrict__ resT, const float* __restrict__ rrW1,
    const float* __restrict__ rrb1, const float* __restrict__ rrW2,
    const float* __restrict__ rrb2, float* relTab){
  int t = threadIdx.x;
  if (blockIdx.x == 2){
    __shared__ float sRT[320], sW1[512], sB1[16], sW2[16];
    for (int i = t; i < 320; i += 256) sRT[i] = resT[i];
    for (int i = t; i < 512; i += 256) sW1[i] = rrW1[i];
    if (t < 16){ sB1[t] = rrb1[t]; sW2[t] = rrW2[t]; }
    __syncthreads();
    float b2v = rrb2[0];
    for (int p = t; p < 400; p += 256){
      int a = p / 20, c = p % 20;
      const float* ra = &sRT[a*16];
      const float* rc = &sRT[c*16];
      float z = b2v;
      #pragma unroll
      for (int j = 0; j < 16; j++){
        float h = sB1[j];
        #pragma unroll
        for (int i = 0; i < 16; i++) h += ra[i] * sW1[i*16+j];
        #pragma unroll
        for (int i = 0; i < 16; i++) h += rc[i] * sW1[(16+i)*16+j];
        z += fmaxf(h, 0.f) * sW2[j];
      }
      relTab[p] = 1.f / (1.f + __expf(-z));
    }
    return;
  }
  int* cnt = blockIdx.x ? cnt_bb : cnt_sc;
  int* rp  = blockIdx.x ? rp_bb  : rp_sc;
  __shared__ int s[256];
  const int CH = 79;
  int beg = t * CH;
  int sum = 0;
  for (int i = beg; i < beg + CH && i < NN; i++) sum += cnt[i];
  s[t] = sum; __syncthreads();
  for (int off = 1; off < 256; off <<= 1){
    int v = (t >= off) ? s[t-off] : 0;
    __syncthreads();
    s[t] += v;
    __syncthreads();
  }
  int run = (t == 0) ? 0 : s[t-1];
  for (int i = beg; i < beg + CH && i < NN; i++){
    int c = cnt[i];
    rp[i] = run;
    cnt[i] = run;      // cursor for scatter
    run += c;
  }
  if (t == 0) rp[NN] = NE;
}

// ---------------- scatter: perm_src + gated sorted edge attrs ----------------
__global__ __launch_bounds__(256) void k_scatter(
    const int* __restrict__ scE, const int* __restrict__ bbE, const int* __restrict__ rid,
    const float* __restrict__ relTab, const float* __restrict__ attrs,
    int* cur_sc, int* cur_bb, int* __restrict__ ps_sc, int* __restrict__ ps_bb,
    float* __restrict__ ea){
  int b = blockIdx.x, t = threadIdx.x;
  if (b < 1250){
    int e = b*256 + t;
    int s = scE[e], d = scE[NE + e];
    float rel = relTab[rid[s]*20 + rid[d]];
    float4 A = ((const float4*)attrs)[e*2];
    float4 B = ((const float4*)attrs)[e*2+1];
    A.x *= rel; A.y *= rel; A.z *= rel; A.w *= rel;
    B.x *= rel; B.y *= rel; B.z *= rel; B.w *= rel;
    int pos = atomicAdd(&cur_sc[d], 1);
    ps_sc[pos] = s;
    ((float4*)ea)[pos*2]   = A;
    ((float4*)ea)[pos*2+1] = B;
  } else {
    int e = (b-1250)*256 + t;
    int s = bbE[e], d = bbE[NE + e];
    int pos = atomicAdd(&cur_bb[d], 1);
    ps_bb[pos] = s;
  }
}

// ---------------- per-layer: edge update + node matmuls ----------------
// grid roles: [0,1250) edge update, [1250,1875) sc node mm (32 nodes/blk),
//             [1875,2500) bb node mm (32 nodes/blk)
// node_mm uses ds_read_b128 (4 k per LDS op) — scalar broadcast reads were
// the DS-issue bottleneck (5.8cyc/b32 vs 2cyc/FMA).
__global__ __launch_bounds__(256) void k_layer1(
    float* __restrict__ ea, int l,
    const float* __restrict__ euW1, const float* __restrict__ eub1,
    const float* __restrict__ eug, const float* __restrict__ eube,
    const float* __restrict__ euW2, const float* __restrict__ eub2,
    const float* __restrict__ sc, const float* __restrict__ bbv,
    const float* __restrict__ scWl, const float* __restrict__ scWr,
    const float* __restrict__ scRes, const float* __restrict__ scBias,
    const float* __restrict__ bbWl, const float* __restrict__ bbWr,
    const float* __restrict__ bbRes, const float* __restrict__ bbBias,
    float* __restrict__ xl_sc, float* __restrict__ xr_sc, float* __restrict__ bs_sc,
    float* __restrict__ xl_bb, float* __restrict__ xr_bb, float* __restrict__ bs_bb){
  __shared__ float smem[2048];
  int b = blockIdx.x, t = threadIdx.x;
  if (b < 1250){
    float* sW1 = smem;        float* sB1 = smem+128; float* sG  = smem+144;
    float* sBe = smem+160;    float* sW2 = smem+176; float* sB2 = smem+304;
    for (int i = t; i < 128; i += 256){ sW1[i] = euW1[l*128+i]; sW2[i] = euW2[l*128+i]; }
    if (t < 16){ sB1[t] = eub1[l*16+t]; sG[t] = eug[l*16+t]; sBe[t] = eube[l*16+t]; }
    if (t < 8) sB2[t] = eub2[l*8+t];
    __syncthreads();
    int e = b*256 + t;
    float4 A = ((const float4*)ea)[e*2];
    float4 B = ((const float4*)ea)[e*2+1];
    float a[8] = {A.x,A.y,A.z,A.w,B.x,B.y,B.z,B.w};
    float h[16];
    #pragma unroll
    for (int j = 0; j < 16; j++){
      float v = sB1[j];
      #pragma unroll
      for (int i = 0; i < 8; i++) v += a[i] * sW1[i*16+j];
      h[j] = fmaxf(v*BN_C*sG[j] + sBe[j], 0.f);
    }
    #pragma unroll
    for (int i = 0; i < 8; i++){
      float v = sB2[i] + a[i];
      #pragma unroll
      for (int j = 0; j < 16; j++) v += h[j] * sW2[j*8+i];
      a[i] = v;
    }
    ((float4*)ea)[e*2]   = make_float4(a[0],a[1],a[2],a[3]);
    ((float4*)ea)[e*2+1] = make_float4(a[4],a[5],a[6],a[7]);
  } else {
    bool is_sc = b < 1875;
    int tile = is_sc ? (b-1250) : (b-1875);
    const float* x  = is_sc ? sc : bbv;
    const float* Wl = is_sc ? scWl : bbWl;
    const float* Wr = is_sc ? scWr : bbWr;
    const float* Ws = is_sc ? scRes : bbRes;
    const float* bias = is_sc ? scBias : bbBias;
    float* xl = is_sc ? xl_sc : xl_bb;
    float* xr = is_sc ? xr_sc : xr_bb;
    float* bs = is_sc ? bs_sc : bs_bb;
    for (int i = t; i < 2048; i += 256) smem[i] = x[tile*2048 + i];
    __syncthreads();
    int d = t & 63, r = t >> 6;
    int wo = l*4096 + d;
    float aL[8] = {0,0,0,0,0,0,0,0}, aR[8] = {0,0,0,0,0,0,0,0}, aB[8];
    float bv = bias[l*64 + d];
    #pragma unroll
    for (int j = 0; j < 8; j++) aB[j] = bv;
    #pragma unroll 2
    for (int k4 = 0; k4 < 16; k4++){
      float4 xv[8];
      #pragma unroll
      for (int j = 0; j < 8; j++) xv[j] = ((const float4*)smem)[(r + 4*j)*16 + k4];
      #pragma unroll
      for (int kk = 0; kk < 4; kk++){
        int k = k4*4 + kk;
        float wl = Wl[wo + k*64], wr = Wr[wo + k*64], ws = Ws[wo + k*64];
        #pragma unroll
        for (int j = 0; j < 8; j++){
          float xvv = f4c(xv[j], kk);
          aL[j] += xvv*wl; aR[j] += xvv*wr; aB[j] += xvv*ws;
        }
      }
    }
    int n0 = tile*32 + r;
    #pragma unroll
    for (int j = 0; j < 8; j++){
      int n = n0 + 4*j;
      xl[n*64+d] = aL[j]; xr[n*64+d] = aR[j]; bs[n*64+d] = aB[j];
    }
  }
}

// ---------------- GAT aggregation: half-wave per edge + gather prefetch (R9) ----------------
// grid: [0,5000) sc graph, [5000,10000) bb graph; 4 waves/block
__global__ __launch_bounds__(256) void k_agg(
    float* __restrict__ sc, float* __restrict__ bbv, int l,
    const float* __restrict__ xl_sc, const float* __restrict__ xr_sc, const float* __restrict__ bs_sc,
    const float* __restrict__ xl_bb, const float* __restrict__ xr_bb, const float* __restrict__ bs_bb,
    const int* __restrict__ rp_sc, const int* __restrict__ ps_sc,
    const int* __restrict__ rp_bb, const int* __restrict__ ps_bb,
    const float* __restrict__ ea, const float* __restrict__ We,
    const float* __restrict__ scAtt, const float* __restrict__ bbAtt){
  int b = blockIdx.x;
  int lane = threadIdx.x & 63, wid = threadIdx.x >> 6;
  int half = lane >> 5, l2 = lane & 31;
  bool is_sc = b < 5000;
  int n = (is_sc ? b : b - 5000)*4 + wid;
  const float* xl = is_sc ? xl_sc : xl_bb;
  const float* xr = is_sc ? xr_sc : xr_bb;
  const float* bs = is_sc ? bs_sc : bs_bb;
  const int* rp = is_sc ? rp_sc : rp_bb;
  const int* ps = is_sc ? ps_sc : ps_bb;
  const float2* xl2 = (const float2*)xl;
  float2 att2 = ((const float2*)((is_sc ? scAtt : bbAtt) + l*64))[l2];
  float2 w[8];
  if (is_sc){
    #pragma unroll
    for (int j = 0; j < 8; j++) w[j] = ((const float2*)(We + l*512 + j*64))[l2];
  }
  int beg = rp[n], end = rp[n+1];
  float2 xr2 = ((const float2*)xr)[n*32 + l2];
  float ox = 0.f, oy = 0.f, s = 0.f;
  if (beg < end){
    int last = end - 1;
    int ia = min(beg + half, last);
    int ib = min(beg + 2 + half, last);
    float2 vA = xl2[ps[ia]*32 + l2];
    float2 vB = xl2[ps[ib]*32 + l2];
    for (int eid = beg; eid < end; eid += 4){
      int nx = eid + 4;
      int ia_n = min(nx + half, last);
      int ib_n = min(nx + 2 + half, last);
      float2 vA_n = xl2[ps[ia_n]*32 + l2];
      float2 vB_n = xl2[ps[ib_n]*32 + l2];
      bool va = eid + half < end;
      bool vb = eid + 2 + half < end;
      float mAx = vA.x + xr2.x, mAy = vA.y + xr2.y;
      float mBx = vB.x + xr2.x, mBy = vB.y + xr2.y;
      if (is_sc){
        int cia = min(eid + half, last);
        int cib = min(eid + 2 + half, last);
        const float4* pa4 = (const float4*)(ea + (size_t)cia*8);
        float4 A = pa4[0], B = pa4[1];
        float av[8] = {A.x,A.y,A.z,A.w,B.x,B.y,B.z,B.w};
        #pragma unroll
        for (int j = 0; j < 8; j++){ mAx += av[j]*w[j].x; mAy += av[j]*w[j].y; }
        const float4* pb4 = (const float4*)(ea + (size_t)cib*8);
        A = pb4[0]; B = pb4[1];
        float bvv[8] = {A.x,A.y,A.z,A.w,B.x,B.y,B.z,B.w};
        #pragma unroll
        for (int j = 0; j < 8; j++){ mBx += bvv[j]*w[j].x; mBy += bvv[j]*w[j].y; }
      }
      float eA = leaky(mAx)*att2.x + leaky(mAy)*att2.y;
      float eB = leaky(mBx)*att2.x + leaky(mBy)*att2.y;
      #pragma unroll
      for (int off = 1; off <= 16; off <<= 1){
        eA += __shfl_xor(eA, off);
        eB += __shfl_xor(eB, off);
      }
      float pA = va ? __expf(eA) : 0.f;
      float pB = vb ? __expf(eB) : 0.f;
      ox += pA*vA.x + pB*vB.x;
      oy += pA*vA.y + pB*vB.y;
      s  += pA + pB;
      vA = vA_n; vB = vB_n;
    }
  }
  ox += __shfl_xor(ox, 32);
  oy += __shfl_xor(oy, 32);
  s  += __shfl_xor(s, 32);
  if (half == 0){
    float2 bsv = ((const float2*)bs)[n*32 + l2];
    float inv = 1.f/(s + 1e-16f);
    float2 r;
    r.x = ox*inv + bsv.x;
    r.y = oy*inv + bsv.y;
    ((float2*)(is_sc ? sc : bbv))[n*32 + l2] = r;
  }
}

// ---------------- heads: chi (sc) | fusion + v_com + backbone heads (bb) ----------------
// All matmul loops use ds_read_b128 (4 k per LDS op).
__global__ __launch_bounds__(256) void k_heads(
    const float* __restrict__ sc, const float* __restrict__ bbv, const int* __restrict__ rid,
    const float* __restrict__ bnuW, const float* __restrict__ bnub,
    const float* __restrict__ bnug, const float* __restrict__ bnube,
    const float* __restrict__ afW, const float* __restrict__ afb,
    const float* __restrict__ afg, const float* __restrict__ afbe,
    const float* __restrict__ vcW1, const float* __restrict__ vcb1,
    const float* __restrict__ vcW2, const float* __restrict__ vcb2,
    const float* __restrict__ chiW, const float* __restrict__ chib,
    const float* __restrict__ adW1, const float* __restrict__ adW2,
    const float* __restrict__ bbhW1, const float* __restrict__ bbhb1,
    const float* __restrict__ phiW2, const float* __restrict__ psiW2,
    const float* __restrict__ xcaW2, const float* __restrict__ xcab2,
    const float* __restrict__ vcbW2, const float* __restrict__ vcbb2,
    float* __restrict__ out){
  __shared__ float sx[1024];
  __shared__ float sh[1024];
  __shared__ int srid[16];
  int b = blockIdx.x, t = threadIdx.x;
  int d = t & 63, r = t >> 6;
  if (b < 1250){
    int tile = b;
    for (int i = t; i < 1024; i += 256) sx[i] = sc[tile*1024 + i];
    if (t < 16) srid[t] = rid[tile*16 + t];
    __syncthreads();
    for (int i = 0; i < 4; i++){
      const float* W = chiW + i*4096;
      float acc[4] = {0,0,0,0};
      #pragma unroll 2
      for (int k4 = 0; k4 < 16; k4++){
        float4 xv[4];
        #pragma unroll
        for (int j = 0; j < 4; j++) xv[j] = ((const float4*)sx)[(r + 4*j)*16 + k4];
        #pragma unroll
        for (int kk = 0; kk < 4; kk++){
          float w = W[(k4*4+kk)*64 + d];
          #pragma unroll
          for (int j = 0; j < 4; j++) acc[j] += f4c(xv[j], kk) * w;
        }
      }
      float bi = chib[i*64+d];
      #pragma unroll
      for (int j = 0; j < 4; j++){
        float mk = chi_mask(srid[r + 4*j], i);
        sh[(r + 4*j)*64 + d] = fmaxf(acc[j] + bi, 0.f) * mk;
      }
      __syncthreads();
      float a2[4] = {0,0,0,0};
      #pragma unroll 2
      for (int k4 = 0; k4 < 16; k4++){
        float4 xv[4];
        #pragma unroll
        for (int j = 0; j < 4; j++) xv[j] = ((const float4*)sh)[(r + 4*j)*16 + k4];
        #pragma unroll
        for (int kk = 0; kk < 4; kk++){
          float w = adW1[(k4*4+kk)*64 + d];
          #pragma unroll
          for (int j = 0; j < 4; j++) a2[j] += f4c(xv[j], kk) * w;
        }
      }
      float w2 = adW2[d];
      #pragma unroll
      for (int j = 0; j < 4; j++){
        float p = wsum(fmaxf(a2[j], 0.f) * w2);
        if (d == 0) out[i*NN + tile*16 + r + 4*j] = p;
      }
      __syncthreads();
    }
  } else {
    int tile = b - 1250;
    for (int i = t; i < 1024; i += 256){ sx[i] = sc[tile*1024 + i]; sh[i] = bbv[tile*1024 + i]; }
    __syncthreads();
    float aU[4] = {0,0,0,0}, aV[4] = {0,0,0,0};
    #pragma unroll 2
    for (int k4 = 0; k4 < 16; k4++){
      float4 xv[4];
      #pragma unroll
      for (int j = 0; j < 4; j++) xv[j] = ((const float4*)sx)[(r + 4*j)*16 + k4];
      #pragma unroll
      for (int kk = 0; kk < 4; kk++){
        int k = k4*4 + kk;
        float wu = bnuW[k*64+d], wv = vcW1[k*64+d];
        #pragma unroll
        for (int j = 0; j < 4; j++){
          float xvv = f4c(xv[j], kk);
          aU[j] += xvv*wu; aV[j] += xvv*wv;
        }
      }
    }
    float afwd = afW[d];
    float bnubd = bnub[d], bnugd = bnug[d], bnubed = bnube[d];
    float vcb1d = vcb1[d];
    float afbv = afb[0], afgv = afg[0], afbev = afbe[0];
    #pragma unroll
    for (int j = 0; j < 4; j++){
      int node = tile*16 + r + 4*j;
      float z = wsum(sx[(r + 4*j)*64 + d] * afwd);
      float attn = 1.f / (1.f + __expf(-((z + afbv)*BN_C*afgv + afbev)));
      float u = fmaxf((aU[j] + bnubd)*BN_C*bnugd + bnubed, 0.f);
      sh[(r + 4*j)*64 + d] += attn*u;
      float vh = fmaxf(aV[j] + vcb1d, 0.f);
      #pragma unroll
      for (int c = 0; c < 3; c++){
        float p = wsum(vh * vcW2[d*3+c]);
        if (d == 0) out[4*NN + node*3 + c] = p + vcb2[c];
      }
    }
    __syncthreads();
    for (int i = 0; i < 4; i++){
      const float* W = bbhW1 + i*4096;
      float acc[4] = {0,0,0,0};
      #pragma unroll 2
      for (int k4 = 0; k4 < 16; k4++){
        float4 xv[4];
        #pragma unroll
        for (int j = 0; j < 4; j++) xv[j] = ((const float4*)sh)[(r + 4*j)*16 + k4];
        #pragma unroll
        for (int kk = 0; kk < 4; kk++){
          float w = W[(k4*4+kk)*64 + d];
          #pragma unroll
          for (int j = 0; j < 4; j++) acc[j] += f4c(xv[j], kk) * w;
        }
      }
      float bi = bbhb1[i*64+d];
      if (i < 2){
        float w2 = (i == 0) ? phiW2[d] : psiW2[d];
        #pragma unroll
        for (int j = 0; j < 4; j++){
          float p = wsum(fmaxf(acc[j] + bi, 0.f) * w2);
          if (d == 0) out[(7+i)*NN + tile*16 + r + 4*j] = p;
        }
      } else {
        const float* W2 = (i == 2) ? xcaW2 : vcbW2;
        const float* B2 = (i == 2) ? xcab2 : vcbb2;
        int off = (i == 2) ? 9*NN : 12*NN;
        #pragma unroll
        for (int j = 0; j < 4; j++){
          float h = fmaxf(acc[j] + bi, 0.f);
          #pragma unroll
          for (int c = 0; c < 3; c++){
            float p = wsum(h * W2[d*3+c]);
            if (d == 0) out[off + (tile*16 + r + 4*j)*3 + c] = p + B2[c];
          }
        }
      }
    }
  }
}

extern "C" __attribute__((visibility("default")))
void kernel_launch(void* const* d_in, const int* in_sizes, int n_in,
                   void* d_out, int out_size, void* d_ws, size_t ws_size,
                   hipStream_t stream) {
  (void)hipGetLastError();

  const float* Xsc   = (const float*)d_in[0];
  const float* Xbb   = (const float*)d_in[1];
  const float* attrs = (const float*)d_in[2];
  const int*  scE   = (const int*)d_in[3];
  const int*  bbE   = (const int*)d_in[4];
  const int*  rid   = (const int*)d_in[5];
  const float* scembW=(const float*)d_in[6];  const float* scembb=(const float*)d_in[7];
  const float* bbembW=(const float*)d_in[8];  const float* bbembb=(const float*)d_in[9];
  const float* resT  =(const float*)d_in[10];
  const float* rrW1  =(const float*)d_in[11]; const float* rrb1  =(const float*)d_in[12];
  const float* rrW2  =(const float*)d_in[13]; const float* rrb2  =(const float*)d_in[14];
  const float* scWl  =(const float*)d_in[15]; const float* scWr  =(const float*)d_in[16];
  const float* scWe  =(const float*)d_in[17]; const float* scAtt =(const float*)d_in[18];
  const float* scRes =(const float*)d_in[19]; const float* scBias=(const float*)d_in[20];
  const float* bbWl  =(const float*)d_in[21]; const float* bbWr  =(const float*)d_in[22];
  const float* bbAtt =(const float*)d_in[23]; const float* bbRes =(const float*)d_in[24];
  const float* bbBias=(const float*)d_in[25];
  const float* euW1  =(const float*)d_in[26]; const float* eub1  =(const float*)d_in[27];
  const float* eug   =(const float*)d_in[28]; const float* eube  =(const float*)d_in[29];
  const float* euW2  =(const float*)d_in[30]; const float* eub2  =(const float*)d_in[31];
  const float* bnuW  =(const float*)d_in[32]; const float* bnub  =(const float*)d_in[33];
  const float* bnug  =(const float*)d_in[34]; const float* bnube =(const float*)d_in[35];
  const float* afW   =(const float*)d_in[36]; const float* afb   =(const float*)d_in[37];
  const float* afg   =(const float*)d_in[38]; const float* afbe  =(const float*)d_in[39];
  const float* chiW  =(const float*)d_in[40]; const float* chib  =(const float*)d_in[41];
  const float* adW1  =(const float*)d_in[42]; const float* adW2  =(const float*)d_in[43];
  const float* vcW1  =(const float*)d_in[44]; const float* vcb1  =(const float*)d_in[45];
  const float* vcW2  =(const float*)d_in[46]; const float* vcb2  =(const float*)d_in[47];
  const float* bbhW1 =(const float*)d_in[48]; const float* bbhb1 =(const float*)d_in[49];
  const float* phiW2 =(const float*)d_in[50]; const float* psiW2 =(const float*)d_in[51];
  const float* xcaW2 =(const float*)d_in[52]; const float* xcab2 =(const float*)d_in[53];
  const float* vcbW2 =(const float*)d_in[54]; const float* vcbb2 =(const float*)d_in[55];
  float* out = (float*)d_out;

  size_t need = 1024 + (size_t)(8*NN*64 + NE*8)*4 + (size_t)(2*(NN+1) + 2*NN + 2*NE)*4;
  if (ws_size < need){
    k_mark<<<(NN+255)/256, 256, 0, stream>>>(out);
    return;
  }
  float* relTab = (float*)d_ws;
  float* f = (float*)((char*)d_ws + 1024);
  float* sc    = f; f += NN*64;
  float* bbuf  = f; f += NN*64;
  float* xl_sc = f; f += NN*64;
  float* xr_sc = f; f += NN*64;
  float* bs_sc = f; f += NN*64;
  float* xl_bb = f; f += NN*64;
  float* xr_bb = f; f += NN*64;
  float* bs_bb = f; f += NN*64;
  float* ea    = f; f += NE*8;
  int* ip = (int*)f;
  int* rp_sc  = ip; ip += NN+1;
  int* rp_bb  = ip; ip += NN+1;
  int* cnt_sc = ip; ip += NN;
  int* cnt_bb = ip; ip += NN;
  int* ps_sc  = ip; ip += NE;
  int* ps_bb  = ip; ip += NE;

  k_init<<<(2*NN + 255)/256, 256, 0, stream>>>(cnt_sc, 2*NN);
  k_pre<<<12500, 256, 0, stream>>>(Xsc, Xbb, scembW, scembb, bbembW, bbembb,
                                   scE, bbE, sc, bbuf, cnt_sc, cnt_bb);
  k_scan<<<3, 256, 0, stream>>>(cnt_sc, cnt_bb, rp_sc, rp_bb,
                                resT, rrW1, rrb1, rrW2, rrb2, relTab);
  k_scatter<<<2500, 256, 0, stream>>>(scE, bbE, rid, relTab, attrs,
                                      cnt_sc, cnt_bb, ps_sc, ps_bb, ea);
  for (int l = 0; l < NL; l++){
    k_layer1<<<2500, 256, 0, stream>>>(ea, l,
        euW1, eub1, eug, eube, euW2, eub2,
        sc, bbuf,
        scWl, scWr, scRes, scBias,
        bbWl, bbWr, bbRes, bbBias,
        xl_sc, xr_sc, bs_sc, xl_bb, xr_bb, bs_bb);
    k_agg<<<10000, 256, 0, stream>>>(sc, bbuf, l,
        xl_sc, xr_sc, bs_sc, xl_bb, xr_bb, bs_bb,
        rp_sc, ps_sc, rp_bb, ps_bb,
        ea, scWe, scAtt, bbAtt);
  }
  k_heads<<<2500, 256, 0, stream>>>(sc, bbuf, rid,
      bnuW, bnub, bnug, bnube, afW, afb, afg, afbe,
      vcW1, vcb1, vcW2, vcb2,
      chiW, chib, adW1, adW2, bbhW1, bbhb1,
      phiW2, psiW2, xcaW2, xcab2, vcbW2, vcbb2, out);
}